// Round 4
// baseline (587.348 us; speedup 1.0000x reference)
//
#include <hip/hip_runtime.h>
#include <hip/hip_bf16.h>

#define NPTS 4096
#define CIN 64
#define COUT 128
#define BATCH 8
#define KNN 8
#define NCAND 16
#define TOTROWS (BATCH * NPTS)   // 32768

using short8 = __attribute__((ext_vector_type(8))) short;
using f32x4  = __attribute__((ext_vector_type(4))) float;

__device__ __forceinline__ unsigned short f2bf_rne(float f) {
    unsigned int u = __float_as_uint(f);
    unsigned int r = (u + 0x7fffu + ((u >> 16) & 1u)) >> 16;
    return (unsigned short)r;
}

// split one fp32 into hi (truncated bf16) + lo (bf16 RNE of residual)
__device__ __forceinline__ void split1(float f, unsigned int& hb, unsigned short& lb) {
    unsigned int b  = __float_as_uint(f);
    unsigned int hm = b & 0xFFFF0000u;
    float lo = f - __uint_as_float(hm);
    hb = hm >> 16;
    lb = f2bf_rne(lo);
}

// convert 8 consecutive floats -> packed hi uint4 + lo uint4 (bf16 pairs)
__device__ __forceinline__ void cvt8(const float* __restrict__ src, uint4& hi, uint4& lo) {
    unsigned int  h[8]; unsigned short l[8];
    #pragma unroll
    for (int j = 0; j < 8; ++j) split1(src[j], h[j], l[j]);
    hi.x = h[0] | (h[1] << 16); hi.y = h[2] | (h[3] << 16);
    hi.z = h[4] | (h[5] << 16); hi.w = h[6] | (h[7] << 16);
    lo.x = (unsigned int)l[0] | ((unsigned int)l[1] << 16);
    lo.y = (unsigned int)l[2] | ((unsigned int)l[3] << 16);
    lo.z = (unsigned int)l[4] | ((unsigned int)l[5] << 16);
    lo.w = (unsigned int)l[6] | ((unsigned int)l[7] << 16);
}

// ---------------- Kernel 1: exact row squared norms (fp64 + fp32 copy) ----------------
__global__ __launch_bounds__(256) void xx_kernel(const float* __restrict__ x,
                                                 float* __restrict__ xxf,
                                                 double* __restrict__ xxd) {
    int i = blockIdx.x * 256 + threadIdx.x;   // 0..32767
    const float4* p = (const float4*)(x + (size_t)i * CIN);
    double s = 0.0;
    #pragma unroll
    for (int c = 0; c < 16; ++c) {
        float4 v = p[c];
        s += (double)v.x * v.x + (double)v.y * v.y + (double)v.z * v.z + (double)v.w * v.w;
    }
    xxf[i] = (float)s;
    xxd[i] = s;
}

// ---------------- Kernel 2: approx scores (split-bf16 MFMA) -> top-16 candidate indices ----------------
// Score(n,m) = 2*inner(n,m) - xx[m]  (xx[n] dropped: per-row constant, ordering unchanged)
// Union of 4 per-thread top-8 lists (disjoint column ranges) provably contains exact top-8;
// merge keeps approx-top-16 of the 32 -> exact top-8 is inside (noise 6e-5 << gaps ~0.76).
__global__ __launch_bounds__(256) void knn_cand_kernel(const float* __restrict__ x,
                                                       const float* __restrict__ xxf,
                                                       int* __restrict__ cand) {
    __shared__ __align__(16) unsigned short As[64 * 136];
    __shared__ __align__(16) unsigned short Bs[64 * 136];
    __shared__ float Sf[64 * 66];
    __shared__ float xxm[64];

    const int tid  = threadIdx.x;
    const int b    = blockIdx.y;
    const int n0   = blockIdx.x * 64;
    const int wave = tid >> 6;
    const int lane = tid & 63;
    const int lrow = lane & 15;
    const int quad = lane >> 4;

    const float* xb = x + (size_t)b * NPTS * CIN;

    // stage A tile: 64 rows, split fp32 -> hi/lo bf16
    for (int c = tid; c < 512; c += 256) {
        int row = c >> 3, col8 = c & 7;
        uint4 hi, lo;
        cvt8(&xb[(size_t)(n0 + row) * CIN + col8 * 8], hi, lo);
        *(uint4*)&As[row * 136 + col8 * 8]      = hi;
        *(uint4*)&As[row * 136 + 64 + col8 * 8] = lo;
    }
    __syncthreads();

    const int arow = (wave * 16 + lrow) * 136;
    short8 ah0 = *(const short8*)&As[arow + quad * 8];
    short8 ah1 = *(const short8*)&As[arow + 32 + quad * 8];
    short8 al0 = *(const short8*)&As[arow + 64 + quad * 8];
    short8 al1 = *(const short8*)&As[arow + 96 + quad * 8];
    __syncthreads();   // A frags in registers; As may be reused later

    float bd[8]; int bi[8];
    #pragma unroll
    for (int j = 0; j < 8; ++j) { bd[j] = -3.0e38f; bi[j] = 0; }
    const int srow = tid >> 2, sq = tid & 3;

    for (int mt = 0; mt < 64; ++mt) {
        for (int c = tid; c < 512; c += 256) {
            int row = c >> 3, col8 = c & 7;
            uint4 hi, lo;
            cvt8(&xb[(size_t)(mt * 64 + row) * CIN + col8 * 8], hi, lo);
            *(uint4*)&Bs[row * 136 + col8 * 8]      = hi;
            *(uint4*)&Bs[row * 136 + 64 + col8 * 8] = lo;
        }
        if (tid < 64) xxm[tid] = xxf[b * NPTS + mt * 64 + tid];
        __syncthreads();

        #pragma unroll
        for (int ct = 0; ct < 4; ++ct) {
            const int brow = (ct * 16 + lrow) * 136;
            short8 bh0 = *(const short8*)&Bs[brow + quad * 8];
            short8 bh1 = *(const short8*)&Bs[brow + 32 + quad * 8];
            short8 bl0 = *(const short8*)&Bs[brow + 64 + quad * 8];
            short8 bl1 = *(const short8*)&Bs[brow + 96 + quad * 8];
            f32x4 acc = {0.f, 0.f, 0.f, 0.f};
            acc = __builtin_amdgcn_mfma_f32_16x16x32_bf16(al0, bl0, acc, 0, 0, 0);
            acc = __builtin_amdgcn_mfma_f32_16x16x32_bf16(al1, bl1, acc, 0, 0, 0);
            acc = __builtin_amdgcn_mfma_f32_16x16x32_bf16(ah0, bl0, acc, 0, 0, 0);
            acc = __builtin_amdgcn_mfma_f32_16x16x32_bf16(ah1, bl1, acc, 0, 0, 0);
            acc = __builtin_amdgcn_mfma_f32_16x16x32_bf16(al0, bh0, acc, 0, 0, 0);
            acc = __builtin_amdgcn_mfma_f32_16x16x32_bf16(al1, bh1, acc, 0, 0, 0);
            acc = __builtin_amdgcn_mfma_f32_16x16x32_bf16(ah0, bh0, acc, 0, 0, 0);
            acc = __builtin_amdgcn_mfma_f32_16x16x32_bf16(ah1, bh1, acc, 0, 0, 0);
            float xm = xxm[ct * 16 + lrow];
            #pragma unroll
            for (int r = 0; r < 4; ++r) {
                Sf[(wave * 16 + quad * 4 + r) * 66 + ct * 16 + lrow] = 2.f * acc[r] - xm;
            }
        }
        __syncthreads();

        const int mbase = mt * 64 + sq * 16;
        #pragma unroll
        for (int i = 0; i < 16; ++i) {
            float v = Sf[srow * 66 + sq * 16 + i];
            if (v > bd[7]) {
                bd[7] = v; bi[7] = mbase + i;
                #pragma unroll
                for (int j = 7; j > 0; --j) {
                    if (bd[j] > bd[j - 1]) {
                        float td = bd[j]; bd[j] = bd[j - 1]; bd[j - 1] = td;
                        int   ti = bi[j]; bi[j] = bi[j - 1]; bi[j - 1] = ti;
                    }
                }
            }
        }
        __syncthreads();
    }

    // merge scratch overlaid on dead A/B tiles
    float* mD = (float*)As;   // 2048 floats = 8 KB <= 17408 B
    int*   mI = (int*)Bs;
    #pragma unroll
    for (int j = 0; j < 8; ++j) {
        mD[srow * 32 + sq * 8 + j] = bd[j];
        mI[srow * 32 + sq * 8 + j] = bi[j];
    }
    __syncthreads();

    if (tid < 64) {
        float fd[NCAND]; int fi[NCAND];
        #pragma unroll
        for (int j = 0; j < NCAND; ++j) { fd[j] = -3.0e38f; fi[j] = 0; }
        for (int c = 0; c < 32; ++c) {
            float v = mD[tid * 32 + c];
            if (v > fd[NCAND - 1]) {
                fd[NCAND - 1] = v; fi[NCAND - 1] = mI[tid * 32 + c];
                #pragma unroll
                for (int j = NCAND - 1; j > 0; --j) {
                    if (fd[j] > fd[j - 1]) {
                        float td = fd[j]; fd[j] = fd[j - 1]; fd[j - 1] = td;
                        int   ti = fi[j]; fi[j] = fi[j - 1]; fi[j - 1] = ti;
                    }
                }
            }
        }
        int* co = cand + ((size_t)b * NPTS + n0 + tid) * NCAND;
        #pragma unroll
        for (int j = 0; j < NCAND; ++j) co[j] = fi[j];
    }
}

// ---------------- Kernel 3: exact fp64 re-rank of 16 candidates + gather/max -> feat ----------------
__global__ __launch_bounds__(256) void rerank_kernel(const float* __restrict__ x,
                                                     const double* __restrict__ xxd,
                                                     const int* __restrict__ cand,
                                                     float* __restrict__ feat) {
    __shared__ double sc[4][NCAND];
    __shared__ int    si[4][NCAND];
    __shared__ int    sel[4][KNN];
    const int tid = threadIdx.x, wave = tid >> 6, lane = tid & 63;
    const size_t row = (size_t)blockIdx.x * 4 + wave;     // 0..32767
    const int b = (int)(row >> 12);
    const float* xb = x + (((size_t)b) << 12) * CIN;
    const float* xn = x + row * CIN;

    if (lane < NCAND) {
        int m = cand[row * NCAND + lane];
        const float* xm = xb + (size_t)m * CIN;
        double d = 0.0;
        #pragma unroll
        for (int c4 = 0; c4 < 16; ++c4) {
            float4 a = *(const float4*)&xn[c4 * 4];
            float4 v = *(const float4*)&xm[c4 * 4];
            d = fma((double)a.x, (double)v.x, d);
            d = fma((double)a.y, (double)v.y, d);
            d = fma((double)a.z, (double)v.z, d);
            d = fma((double)a.w, (double)v.w, d);
        }
        sc[wave][lane] = 2.0 * d - xxd[(((size_t)b) << 12) + m];
        si[wave][lane] = m;
    }
    __syncthreads();

    if (lane == 0) {
        double fd[KNN]; int fi[KNN];
        #pragma unroll
        for (int j = 0; j < KNN; ++j) { fd[j] = -1.0e300; fi[j] = 0; }
        for (int c = 0; c < NCAND; ++c) {
            double v = sc[wave][c];
            if (v > fd[KNN - 1]) {
                fd[KNN - 1] = v; fi[KNN - 1] = si[wave][c];
                #pragma unroll
                for (int j = KNN - 1; j > 0; --j) {
                    if (fd[j] > fd[j - 1]) {
                        double td = fd[j]; fd[j] = fd[j - 1]; fd[j - 1] = td;
                        int    ti = fi[j]; fi[j] = fi[j - 1]; fi[j - 1] = ti;
                    }
                }
            }
        }
        #pragma unroll
        for (int j = 0; j < KNN; ++j) sel[wave][j] = fi[j];
    }
    __syncthreads();

    float mx = -3.0e38f;
    #pragma unroll
    for (int j = 0; j < KNN; ++j)
        mx = fmaxf(mx, xb[(size_t)sel[wave][j] * CIN + lane]);
    feat[row * CIN + lane] = mx;
}

// ---------------- Kernel 4: conv (fp32 VALU) + BN stats ----------------
__global__ __launch_bounds__(256) void conv_stats_kernel(const float* __restrict__ feat,
                                                         const float* __restrict__ W,
                                                         float* __restrict__ st) {
    __shared__ float Wt[64 * 128];   // Wt[c][o]
    __shared__ float Fs[64 * 64];
    __shared__ float bs[128], bs2[128];
    const int tid = threadIdx.x;
    const int n0  = blockIdx.x * 64;

    for (int i = tid; i < 8192; i += 256) {
        int o = i >> 6, c = i & 63;
        Wt[c * 128 + o] = W[i];
    }
    for (int i = tid; i < 1024; i += 256)
        ((float4*)Fs)[i] = ((const float4*)(feat + (size_t)n0 * CIN))[i];
    if (tid < 128) { bs[tid] = 0.f; bs2[tid] = 0.f; }
    __syncthreads();

    const int og = tid & 31, rg = tid >> 5;
    float ts[4] = {0.f, 0.f, 0.f, 0.f}, ts2[4] = {0.f, 0.f, 0.f, 0.f};
    #pragma unroll
    for (int p = 0; p < 4; ++p) {
        const int r0 = p * 16 + rg * 2;
        float acc0[4] = {0.f, 0.f, 0.f, 0.f}, acc1[4] = {0.f, 0.f, 0.f, 0.f};
        for (int c = 0; c < 64; ++c) {
            float f0 = Fs[r0 * 64 + c], f1 = Fs[(r0 + 1) * 64 + c];
            #pragma unroll
            for (int j = 0; j < 4; ++j) {
                float w = Wt[c * 128 + og + 32 * j];
                acc0[j] += f0 * w; acc1[j] += f1 * w;
            }
        }
        #pragma unroll
        for (int j = 0; j < 4; ++j) {
            ts[j]  += acc0[j] + acc1[j];
            ts2[j] += acc0[j] * acc0[j] + acc1[j] * acc1[j];
        }
    }
    #pragma unroll
    for (int j = 0; j < 4; ++j) {
        atomicAdd(&bs [og + 32 * j], ts[j]);
        atomicAdd(&bs2[og + 32 * j], ts2[j]);
    }
    __syncthreads();
    if (tid < 128) {
        atomicAdd(&st[tid],       bs[tid]);
        atomicAdd(&st[128 + tid], bs2[tid]);
    }
}

// ---------------- Kernel 5: recompute conv, BN + LeakyReLU -> fp32 out ----------------
__global__ __launch_bounds__(256) void norm_out_kernel(const float* __restrict__ feat,
                                                       const float* __restrict__ W,
                                                       const float* __restrict__ st,
                                                       const float* __restrict__ gamma,
                                                       const float* __restrict__ beta,
                                                       float* __restrict__ out) {
    __shared__ float Wt[64 * 128];
    __shared__ float Fs[64 * 64];
    __shared__ float mean_s[128], scale_s[128], beta_s[128];
    const int tid = threadIdx.x;
    const int n0  = blockIdx.x * 64;

    for (int i = tid; i < 8192; i += 256) {
        int o = i >> 6, c = i & 63;
        Wt[c * 128 + o] = W[i];
    }
    for (int i = tid; i < 1024; i += 256)
        ((float4*)Fs)[i] = ((const float4*)(feat + (size_t)n0 * CIN))[i];
    if (tid < 128) {
        const float inv = 1.0f / (float)TOTROWS;
        float m = st[tid] * inv;
        float v = st[128 + tid] * inv - m * m;
        mean_s[tid]  = m;
        scale_s[tid] = rsqrtf(v + 1e-5f) * gamma[tid];
        beta_s[tid]  = beta[tid];
    }
    __syncthreads();

    const int og = tid & 31, rg = tid >> 5;
    #pragma unroll
    for (int p = 0; p < 4; ++p) {
        const int r0 = p * 16 + rg * 2;
        float acc0[4] = {0.f, 0.f, 0.f, 0.f}, acc1[4] = {0.f, 0.f, 0.f, 0.f};
        for (int c = 0; c < 64; ++c) {
            float f0 = Fs[r0 * 64 + c], f1 = Fs[(r0 + 1) * 64 + c];
            #pragma unroll
            for (int j = 0; j < 4; ++j) {
                float w = Wt[c * 128 + og + 32 * j];
                acc0[j] += f0 * w; acc1[j] += f1 * w;
            }
        }
        #pragma unroll
        for (int j = 0; j < 4; ++j) {
            const int ch = og + 32 * j;
            float o0 = (acc0[j] - mean_s[ch]) * scale_s[ch] + beta_s[ch];
            float o1 = (acc1[j] - mean_s[ch]) * scale_s[ch] + beta_s[ch];
            o0 = (o0 >= 0.f) ? o0 : 0.01f * o0;
            o1 = (o1 >= 0.f) ? o1 : 0.01f * o1;
            out[(size_t)(n0 + r0)     * COUT + ch] = o0;
            out[(size_t)(n0 + r0 + 1) * COUT + ch] = o1;
        }
    }
}

extern "C" void kernel_launch(void* const* d_in, const int* in_sizes, int n_in,
                              void* d_out, int out_size, void* d_ws, size_t ws_size,
                              hipStream_t stream) {
    (void)in_sizes; (void)n_in; (void)out_size; (void)ws_size;
    const float* x     = (const float*)d_in[0];
    const float* W     = (const float*)d_in[1];
    const float* gamma = (const float*)d_in[2];
    const float* beta  = (const float*)d_in[3];
    // d_in[4] is k == 8 (compile-time KNN)
    float* out = (float*)d_out;

    // workspace (~10.4 MB): xxf 128K | xxd 256K | cand 2M | feat 8M | st 1K
    char*   ws   = (char*)d_ws;
    float*  xxf  = (float*)ws;                                   // 131072 B
    double* xxd  = (double*)(ws + 131072);                       // 262144 B
    int*    cand = (int*)(ws + 131072 + 262144);                 // 2097152 B
    float*  feat = (float*)(ws + 131072 + 262144 + 2097152);     // 8388608 B
    float*  st   = (float*)(ws + 131072 + 262144 + 2097152 + 8388608);

    hipMemsetAsync(st, 0, 256 * sizeof(float), stream);
    xx_kernel        <<<TOTROWS / 256, 256, 0, stream>>>(x, xxf, xxd);
    knn_cand_kernel  <<<dim3(NPTS / 64, BATCH), 256, 0, stream>>>(x, xxf, cand);
    rerank_kernel    <<<TOTROWS / 4, 256, 0, stream>>>(x, xxd, cand, feat);
    conv_stats_kernel<<<TOTROWS / 64, 256, 0, stream>>>(feat, W, st);
    norm_out_kernel  <<<TOTROWS / 64, 256, 0, stream>>>(feat, W, st, gamma, beta, out);
}

// Round 6
// 468.022 us; speedup vs baseline: 1.2550x; 1.2550x over previous
//
#include <hip/hip_runtime.h>
#include <hip/hip_bf16.h>

#define NPTS 4096
#define CIN 64
#define COUT 128
#define BATCH 8
#define KNN 8
#define NCH 16              // candidates per column-half
#define NCT 32              // total candidates per row
#define TOTROWS (BATCH * NPTS)   // 32768

using short8 = __attribute__((ext_vector_type(8))) short;
using f32x4  = __attribute__((ext_vector_type(4))) float;

__device__ __forceinline__ unsigned short f2bf_rne(float f) {
    unsigned int u = __float_as_uint(f);
    unsigned int r = (u + 0x7fffu + ((u >> 16) & 1u)) >> 16;
    return (unsigned short)r;
}

// ---------------- Kernel 1: pack x -> hi/lo bf16 rows (256B) + exact row norms ----------------
// xpack row layout (128 ushorts): [hi cols 0..63][lo cols 0..63]
__global__ __launch_bounds__(256) void prep_kernel(const float* __restrict__ x,
                                                   unsigned short* __restrict__ xpack,
                                                   float* __restrict__ xxf,
                                                   double* __restrict__ xxd) {
    int i   = blockIdx.x * 256 + threadIdx.x;    // 0 .. 262143
    int row = i >> 3, g = i & 7;                 // 8 threads per row
    const float* src = x + (size_t)row * CIN + g * 8;
    float4 v0 = *(const float4*)src;
    float4 v1 = *(const float4*)(src + 4);
    float f[8] = {v0.x, v0.y, v0.z, v0.w, v1.x, v1.y, v1.z, v1.w};

    unsigned int h[8]; unsigned short l[8];
    double s = 0.0;
    #pragma unroll
    for (int j = 0; j < 8; ++j) {
        unsigned int b  = __float_as_uint(f[j]);
        unsigned int hm = b & 0xFFFF0000u;
        h[j] = hm >> 16;
        l[j] = f2bf_rne(f[j] - __uint_as_float(hm));
        s += (double)f[j] * (double)f[j];
    }
    uint4 hi, lo;
    hi.x = h[0] | (h[1] << 16); hi.y = h[2] | (h[3] << 16);
    hi.z = h[4] | (h[5] << 16); hi.w = h[6] | (h[7] << 16);
    lo.x = (unsigned int)l[0] | ((unsigned int)l[1] << 16);
    lo.y = (unsigned int)l[2] | ((unsigned int)l[3] << 16);
    lo.z = (unsigned int)l[4] | ((unsigned int)l[5] << 16);
    lo.w = (unsigned int)l[6] | ((unsigned int)l[7] << 16);
    unsigned short* dst = xpack + (size_t)row * 128;
    *(uint4*)&dst[g * 8]      = hi;
    *(uint4*)&dst[64 + g * 8] = lo;

    // reduce squared norm across the 8 lanes of this row group
    s += __shfl_xor(s, 1);
    s += __shfl_xor(s, 2);
    s += __shfl_xor(s, 4);
    if (g == 0) { xxf[row] = (float)s; xxd[row] = s; }
}

// ---------------- Kernel 2: approx scores (split-bf16 MFMA) -> per-half top-16 candidates ----------------
// grid (64, 2, 8): 64 rows x 2048 candidate cols per block. 1 barrier per tile.
__global__ __launch_bounds__(256, 4) void knn_cand_kernel(const unsigned short* __restrict__ xpack,
                                                          const float* __restrict__ xxf,
                                                          int* __restrict__ cand) {
    __shared__ __align__(16) unsigned short P0[64 * 136];
    __shared__ __align__(16) unsigned short P1[64 * 136];
    __shared__ float Sf[4][16 * 17];
    __shared__ float xxm[2][64];

    const int tid  = threadIdx.x;
    const int n0   = blockIdx.x * 64;
    const int half = blockIdx.y;
    const int b    = blockIdx.z;
    const int wave = tid >> 6;
    const int lane = tid & 63;
    const int lrow = lane & 15;
    const int quad = lane >> 4;
    const int colT0 = half * 32;                 // first 64-col tile of this half

    const unsigned short* xp = xpack + ((size_t)b << 12) * 128;

    // stage A tile (rows n0..n0+63) into P0 (1024 chunks of 16B)
    for (int G = tid; G < 1024; G += 256) {
        int row = G >> 4, g = G & 15;
        *(uint4*)&P0[row * 136 + g * 8] = *(const uint4*)&xp[(size_t)(n0 + row) * 128 + g * 8];
    }
    __syncthreads();

    const int arow = (wave * 16 + lrow) * 136;
    short8 ah0 = *(const short8*)&P0[arow + quad * 8];
    short8 ah1 = *(const short8*)&P0[arow + 32 + quad * 8];
    short8 al0 = *(const short8*)&P0[arow + 64 + quad * 8];
    short8 al1 = *(const short8*)&P0[arow + 96 + quad * 8];

    // stage B tile 0 into P1 — FULL tile: 1024 chunks, 4 per thread
    {
        uint4 r0[4];
        const int G0 = tid * 4;
        #pragma unroll
        for (int k = 0; k < 4; ++k) {
            int G = G0 + k, row = G >> 4, g = G & 15;
            r0[k] = *(const uint4*)&xp[(size_t)(colT0 * 64 + row) * 128 + g * 8];
        }
        float xv = (tid < 64) ? xxf[(b << 12) + colT0 * 64 + tid] : 0.f;
        #pragma unroll
        for (int k = 0; k < 4; ++k) {
            int G = G0 + k, row = G >> 4, g = G & 15;
            *(uint4*)&P1[row * 136 + g * 8] = r0[k];
        }
        if (tid < 64) xxm[0][tid] = xv;
    }
    __syncthreads();

    float bd[8]; int bi[8];
    #pragma unroll
    for (int j = 0; j < 8; ++j) { bd[j] = -3.0e38f; bi[j] = 0; }
    const int srow17 = (lane >> 2) * 17;
    const int cls    = lane & 3;

    for (int mt = 0; mt < 32; ++mt) {
        unsigned short* cur = (mt & 1) ? P0 : P1;
        unsigned short* nxt = (mt & 1) ? P1 : P0;

        // issue prefetch loads for tile mt+1 (consumed after compute)
        uint4 pr[4]; float pxv = 0.f;
        const int G0 = tid * 4;
        if (mt + 1 < 32) {
            const int tnext = colT0 + mt + 1;
            #pragma unroll
            for (int k = 0; k < 4; ++k) {
                int G = G0 + k, row = G >> 4, g = G & 15;
                pr[k] = *(const uint4*)&xp[(size_t)(tnext * 64 + row) * 128 + g * 8];
            }
            if (tid < 64) pxv = xxf[(b << 12) + tnext * 64 + tid];
        }

        const int tbase = (colT0 + mt) * 64;
        #pragma unroll
        for (int ct = 0; ct < 4; ++ct) {
            const int brow = (ct * 16 + lrow) * 136;
            short8 bh0 = *(const short8*)&cur[brow + quad * 8];
            short8 bh1 = *(const short8*)&cur[brow + 32 + quad * 8];
            short8 bl0 = *(const short8*)&cur[brow + 64 + quad * 8];
            short8 bl1 = *(const short8*)&cur[brow + 96 + quad * 8];
            f32x4 acc = {0.f, 0.f, 0.f, 0.f};
            acc = __builtin_amdgcn_mfma_f32_16x16x32_bf16(al0, bl0, acc, 0, 0, 0);
            acc = __builtin_amdgcn_mfma_f32_16x16x32_bf16(al1, bl1, acc, 0, 0, 0);
            acc = __builtin_amdgcn_mfma_f32_16x16x32_bf16(ah0, bl0, acc, 0, 0, 0);
            acc = __builtin_amdgcn_mfma_f32_16x16x32_bf16(ah1, bl1, acc, 0, 0, 0);
            acc = __builtin_amdgcn_mfma_f32_16x16x32_bf16(al0, bh0, acc, 0, 0, 0);
            acc = __builtin_amdgcn_mfma_f32_16x16x32_bf16(al1, bh1, acc, 0, 0, 0);
            acc = __builtin_amdgcn_mfma_f32_16x16x32_bf16(ah0, bh0, acc, 0, 0, 0);
            acc = __builtin_amdgcn_mfma_f32_16x16x32_bf16(ah1, bh1, acc, 0, 0, 0);
            float xm = xxm[mt & 1][ct * 16 + lrow];
            #pragma unroll
            for (int r = 0; r < 4; ++r)
                Sf[wave][(quad * 4 + r) * 17 + lrow] = 2.f * acc[r] - xm;
            asm volatile("s_waitcnt lgkmcnt(0)" ::: "memory");

            // scan: lane owns row (lane>>2), cols cls+4i of this 16-col chunk
            const int cbase = tbase + ct * 16 + cls;
            #pragma unroll
            for (int i = 0; i < 4; ++i) {
                float v = Sf[wave][srow17 + cls + 4 * i];
                if (v > bd[7]) {
                    bd[7] = v; bi[7] = cbase + 4 * i;
                    #pragma unroll
                    for (int j = 7; j > 0; --j) {
                        if (bd[j] > bd[j - 1]) {
                            float td = bd[j]; bd[j] = bd[j - 1]; bd[j - 1] = td;
                            int   ti = bi[j]; bi[j] = bi[j - 1]; bi[j - 1] = ti;
                        }
                    }
                }
            }
            asm volatile("" ::: "memory");
        }

        // complete prefetch into nxt
        if (mt + 1 < 32) {
            #pragma unroll
            for (int k = 0; k < 4; ++k) {
                int G = G0 + k, row = G >> 4, g = G & 15;
                *(uint4*)&nxt[row * 136 + g * 8] = pr[k];
            }
            if (tid < 64) xxm[(mt + 1) & 1][tid] = pxv;
        }
        __syncthreads();
    }

    // merge 4 class-lists per row -> top-16 of this half
    float* mD = (float*)P0;
    int*   mI = (int*)P1;
    const int mrow = wave * 16 + (lane >> 2);
    #pragma unroll
    for (int j = 0; j < 8; ++j) {
        mD[mrow * 32 + cls * 8 + j] = bd[j];
        mI[mrow * 32 + cls * 8 + j] = bi[j];
    }
    __syncthreads();

    if (tid < 64) {
        float fd[NCH]; int fi[NCH];
        #pragma unroll
        for (int j = 0; j < NCH; ++j) { fd[j] = -3.0e38f; fi[j] = 0; }
        for (int c = 0; c < 32; ++c) {
            float v = mD[tid * 32 + c];
            if (v > fd[NCH - 1]) {
                fd[NCH - 1] = v; fi[NCH - 1] = mI[tid * 32 + c];
                #pragma unroll
                for (int j = NCH - 1; j > 0; --j) {
                    if (fd[j] > fd[j - 1]) {
                        float td = fd[j]; fd[j] = fd[j - 1]; fd[j - 1] = td;
                        int   ti = fi[j]; fi[j] = fi[j - 1]; fi[j - 1] = ti;
                    }
                }
            }
        }
        int* co = cand + ((size_t)((b << 12) + n0 + tid)) * NCT + half * NCH;
        #pragma unroll
        for (int j = 0; j < NCH; ++j) co[j] = fi[j];
    }
}

// ---------------- Kernel 3: exact fp64 re-rank of 32 candidates + gather/max -> feat ----------------
__global__ __launch_bounds__(256) void rerank_kernel(const float* __restrict__ x,
                                                     const double* __restrict__ xxd,
                                                     const int* __restrict__ cand,
                                                     float* __restrict__ feat) {
    __shared__ double sc[4][NCT];
    __shared__ int    si[4][NCT];
    __shared__ int    sel[4][KNN];
    const int tid = threadIdx.x, wave = tid >> 6, lane = tid & 63;
    const size_t row = (size_t)blockIdx.x * 4 + wave;     // 0..32767
    const int b = (int)(row >> 12);
    const float* xb = x + (((size_t)b) << 12) * CIN;
    const float* xn = x + row * CIN;

    const int cidx = lane & 31, part = lane >> 5;
    int m = cand[row * NCT + cidx];
    {
        const float* xm = xb + (size_t)m * CIN;
        const float* xa = xn + part * 32;
        const float* xv = xm + part * 32;
        double d = 0.0;
        #pragma unroll
        for (int c4 = 0; c4 < 8; ++c4) {
            float4 a = *(const float4*)&xa[c4 * 4];
            float4 v = *(const float4*)&xv[c4 * 4];
            d = fma((double)a.x, (double)v.x, d);
            d = fma((double)a.y, (double)v.y, d);
            d = fma((double)a.z, (double)v.z, d);
            d = fma((double)a.w, (double)v.w, d);
        }
        d += __shfl_xor(d, 32);
        if (part == 0) {
            sc[wave][cidx] = 2.0 * d - xxd[(((size_t)b) << 12) + m];
            si[wave][cidx] = m;
        }
    }
    __syncthreads();

    if (lane == 0) {
        double fd[KNN]; int fi[KNN];
        #pragma unroll
        for (int j = 0; j < KNN; ++j) { fd[j] = -1.0e300; fi[j] = 0; }
        for (int c = 0; c < NCT; ++c) {
            double v = sc[wave][c];
            if (v > fd[KNN - 1]) {
                fd[KNN - 1] = v; fi[KNN - 1] = si[wave][c];
                #pragma unroll
                for (int j = KNN - 1; j > 0; --j) {
                    if (fd[j] > fd[j - 1]) {
                        double td = fd[j]; fd[j] = fd[j - 1]; fd[j - 1] = td;
                        int    ti = fi[j]; fi[j] = fi[j - 1]; fi[j - 1] = ti;
                    }
                }
            }
        }
        #pragma unroll
        for (int j = 0; j < KNN; ++j) sel[wave][j] = fi[j];
    }
    __syncthreads();

    float mx = -3.0e38f;
    #pragma unroll
    for (int j = 0; j < KNN; ++j)
        mx = fmaxf(mx, xb[(size_t)sel[wave][j] * CIN + lane]);
    feat[row * CIN + lane] = mx;
}

// ---------------- Kernel 4: conv (fp32 VALU) + BN stats ----------------
__global__ __launch_bounds__(256) void conv_stats_kernel(const float* __restrict__ feat,
                                                         const float* __restrict__ W,
                                                         float* __restrict__ st) {
    __shared__ float Wt[64 * 128];   // Wt[c][o]
    __shared__ float Fs[64 * 64];
    __shared__ float bs[128], bs2[128];
    const int tid = threadIdx.x;
    const int n0  = blockIdx.x * 64;

    for (int i = tid; i < 8192; i += 256) {
        int o = i >> 6, c = i & 63;
        Wt[c * 128 + o] = W[i];
    }
    for (int i = tid; i < 1024; i += 256)
        ((float4*)Fs)[i] = ((const float4*)(feat + (size_t)n0 * CIN))[i];
    if (tid < 128) { bs[tid] = 0.f; bs2[tid] = 0.f; }
    __syncthreads();

    const int og = tid & 31, rg = tid >> 5;
    float ts[4] = {0.f, 0.f, 0.f, 0.f}, ts2[4] = {0.f, 0.f, 0.f, 0.f};
    #pragma unroll
    for (int p = 0; p < 4; ++p) {
        const int r0 = p * 16 + rg * 2;
        float acc0[4] = {0.f, 0.f, 0.f, 0.f}, acc1[4] = {0.f, 0.f, 0.f, 0.f};
        for (int c = 0; c < 64; ++c) {
            float f0 = Fs[r0 * 64 + c], f1 = Fs[(r0 + 1) * 64 + c];
            #pragma unroll
            for (int j = 0; j < 4; ++j) {
                float w = Wt[c * 128 + og + 32 * j];
                acc0[j] += f0 * w; acc1[j] += f1 * w;
            }
        }
        #pragma unroll
        for (int j = 0; j < 4; ++j) {
            ts[j]  += acc0[j] + acc1[j];
            ts2[j] += acc0[j] * acc0[j] + acc1[j] * acc1[j];
        }
    }
    #pragma unroll
    for (int j = 0; j < 4; ++j) {
        atomicAdd(&bs [og + 32 * j], ts[j]);
        atomicAdd(&bs2[og + 32 * j], ts2[j]);
    }
    __syncthreads();
    if (tid < 128) {
        atomicAdd(&st[tid],       bs[tid]);
        atomicAdd(&st[128 + tid], bs2[tid]);
    }
}

// ---------------- Kernel 5: recompute conv, BN + LeakyReLU -> fp32 out ----------------
__global__ __launch_bounds__(256) void norm_out_kernel(const float* __restrict__ feat,
                                                       const float* __restrict__ W,
                                                       const float* __restrict__ st,
                                                       const float* __restrict__ gamma,
                                                       const float* __restrict__ beta,
                                                       float* __restrict__ out) {
    __shared__ float Wt[64 * 128];
    __shared__ float Fs[64 * 64];
    __shared__ float mean_s[128], scale_s[128], beta_s[128];
    const int tid = threadIdx.x;
    const int n0  = blockIdx.x * 64;

    for (int i = tid; i < 8192; i += 256) {
        int o = i >> 6, c = i & 63;
        Wt[c * 128 + o] = W[i];
    }
    for (int i = tid; i < 1024; i += 256)
        ((float4*)Fs)[i] = ((const float4*)(feat + (size_t)n0 * CIN))[i];
    if (tid < 128) {
        const float inv = 1.0f / (float)TOTROWS;
        float m = st[tid] * inv;
        float v = st[128 + tid] * inv - m * m;
        mean_s[tid]  = m;
        scale_s[tid] = rsqrtf(v + 1e-5f) * gamma[tid];
        beta_s[tid]  = beta[tid];
    }
    __syncthreads();

    const int og = tid & 31, rg = tid >> 5;
    #pragma unroll
    for (int p = 0; p < 4; ++p) {
        const int r0 = p * 16 + rg * 2;
        float acc0[4] = {0.f, 0.f, 0.f, 0.f}, acc1[4] = {0.f, 0.f, 0.f, 0.f};
        for (int c = 0; c < 64; ++c) {
            float f0 = Fs[r0 * 64 + c], f1 = Fs[(r0 + 1) * 64 + c];
            #pragma unroll
            for (int j = 0; j < 4; ++j) {
                float w = Wt[c * 128 + og + 32 * j];
                acc0[j] += f0 * w; acc1[j] += f1 * w;
            }
        }
        #pragma unroll
        for (int j = 0; j < 4; ++j) {
            const int ch = og + 32 * j;
            float o0 = (acc0[j] - mean_s[ch]) * scale_s[ch] + beta_s[ch];
            float o1 = (acc1[j] - mean_s[ch]) * scale_s[ch] + beta_s[ch];
            o0 = (o0 >= 0.f) ? o0 : 0.01f * o0;
            o1 = (o1 >= 0.f) ? o1 : 0.01f * o1;
            out[(size_t)(n0 + r0)     * COUT + ch] = o0;
            out[(size_t)(n0 + r0 + 1) * COUT + ch] = o1;
        }
    }
}

extern "C" void kernel_launch(void* const* d_in, const int* in_sizes, int n_in,
                              void* d_out, int out_size, void* d_ws, size_t ws_size,
                              hipStream_t stream) {
    (void)in_sizes; (void)n_in; (void)out_size; (void)ws_size;
    const float* x     = (const float*)d_in[0];
    const float* W     = (const float*)d_in[1];
    const float* gamma = (const float*)d_in[2];
    const float* beta  = (const float*)d_in[3];
    // d_in[4] is k == 8 (compile-time KNN)
    float* out = (float*)d_out;

    // workspace (~28.4 MB): xxf 128K | xxd 256K | cand 4M | feat 8M | xpack 16M | st 1K
    char*   ws    = (char*)d_ws;
    float*  xxf   = (float*)ws;                                            // 131072
    double* xxd   = (double*)(ws + 131072);                                // 262144
    int*    cand  = (int*)(ws + 131072 + 262144);                          // 4194304
    float*  feat  = (float*)(ws + 131072 + 262144 + 4194304);              // 8388608
    unsigned short* xpack = (unsigned short*)(ws + 131072 + 262144 + 4194304 + 8388608); // 16 MB
    float*  st    = (float*)(ws + 131072 + 262144 + 4194304 + 8388608 + 16777216);

    hipMemsetAsync(st, 0, 256 * sizeof(float), stream);
    prep_kernel      <<<TOTROWS * 8 / 256, 256, 0, stream>>>(x, xpack, xxf, xxd);
    knn_cand_kernel  <<<dim3(NPTS / 64, 2, BATCH), 256, 0, stream>>>(xpack, xxf, cand);
    rerank_kernel    <<<TOTROWS / 4, 256, 0, stream>>>(x, xxd, cand, feat);
    conv_stats_kernel<<<TOTROWS / 64, 256, 0, stream>>>(feat, W, st);
    norm_out_kernel  <<<TOTROWS / 64, 256, 0, stream>>>(feat, W, st, gamma, beta, out);
}

// Round 7
// 435.159 us; speedup vs baseline: 1.3497x; 1.0755x over previous
//
#include <hip/hip_runtime.h>
#include <hip/hip_bf16.h>

#define NPTS 4096
#define CIN 64
#define COUT 128
#define BATCH 8
#define KNN 8
#define NCH 16              // candidates per column-half
#define NCT 32              // total candidates per row
#define TOTROWS (BATCH * NPTS)   // 32768

using short8 = __attribute__((ext_vector_type(8))) short;
using f32x4  = __attribute__((ext_vector_type(4))) float;

__device__ __forceinline__ unsigned short f2bf_rne(float f) {
    unsigned int u = __float_as_uint(f);
    unsigned int r = (u + 0x7fffu + ((u >> 16) & 1u)) >> 16;
    return (unsigned short)r;
}

// ---------------- Kernel 1: pack x -> hi/lo bf16 rows (256B) + exact row norms ----------------
__global__ __launch_bounds__(256) void prep_kernel(const float* __restrict__ x,
                                                   unsigned short* __restrict__ xpack,
                                                   float* __restrict__ xxf,
                                                   double* __restrict__ xxd) {
    int i   = blockIdx.x * 256 + threadIdx.x;    // 0 .. 262143
    int row = i >> 3, g = i & 7;                 // 8 threads per row
    const float* src = x + (size_t)row * CIN + g * 8;
    float4 v0 = *(const float4*)src;
    float4 v1 = *(const float4*)(src + 4);
    float f[8] = {v0.x, v0.y, v0.z, v0.w, v1.x, v1.y, v1.z, v1.w};

    unsigned int h[8]; unsigned short l[8];
    double s = 0.0;
    #pragma unroll
    for (int j = 0; j < 8; ++j) {
        unsigned int b  = __float_as_uint(f[j]);
        unsigned int hm = b & 0xFFFF0000u;
        h[j] = hm >> 16;
        l[j] = f2bf_rne(f[j] - __uint_as_float(hm));
        s += (double)f[j] * (double)f[j];
    }
    uint4 hi, lo;
    hi.x = h[0] | (h[1] << 16); hi.y = h[2] | (h[3] << 16);
    hi.z = h[4] | (h[5] << 16); hi.w = h[6] | (h[7] << 16);
    lo.x = (unsigned int)l[0] | ((unsigned int)l[1] << 16);
    lo.y = (unsigned int)l[2] | ((unsigned int)l[3] << 16);
    lo.z = (unsigned int)l[4] | ((unsigned int)l[5] << 16);
    lo.w = (unsigned int)l[6] | ((unsigned int)l[7] << 16);
    unsigned short* dst = xpack + (size_t)row * 128;
    *(uint4*)&dst[g * 8]      = hi;
    *(uint4*)&dst[64 + g * 8] = lo;

    s += __shfl_xor(s, 1);
    s += __shfl_xor(s, 2);
    s += __shfl_xor(s, 4);
    if (g == 0) { xxf[row] = (float)s; xxd[row] = s; }
}

// ---------------- Kernel 2: split-bf16 MFMA scores -> sortable-key top-8/lane -> top-16/half ----------------
// key = sortable_u32(score) with low 7 bits replaced by stream position p = mt*4+ct.
// Truncation error <= 2^(exp-16) ~ 0.004 << candidate margin; rerank is exact fp64 anyway.
__global__ __launch_bounds__(256, 4) void knn_cand_kernel(const unsigned short* __restrict__ xpack,
                                                          const float* __restrict__ xxf,
                                                          int* __restrict__ cand) {
    __shared__ __align__(16) unsigned short P[2][64 * 136];
    __shared__ float xxm[2][64];

    const int tid  = threadIdx.x;
    const int n0   = blockIdx.x * 64;
    const int half = blockIdx.y;
    const int b    = blockIdx.z;
    const int wave = tid >> 6;
    const int lane = tid & 63;
    const int lrow = lane & 15;
    const int quad = lane >> 4;
    const int colT0 = half * 32;                 // first 64-col tile of this half

    const unsigned short* xp = xpack + ((size_t)b << 12) * 128;

    // stage A tile (rows n0..n0+63) into P[0]
    for (int G = tid; G < 1024; G += 256) {
        int row = G >> 4, g = G & 15;
        *(uint4*)&P[0][row * 136 + g * 8] = *(const uint4*)&xp[(size_t)(n0 + row) * 128 + g * 8];
    }
    __syncthreads();

    const int arow = (wave * 16 + lrow) * 136;
    short8 ah0 = *(const short8*)&P[0][arow + quad * 8];
    short8 ah1 = *(const short8*)&P[0][arow + 32 + quad * 8];
    short8 al0 = *(const short8*)&P[0][arow + 64 + quad * 8];
    short8 al1 = *(const short8*)&P[0][arow + 96 + quad * 8];

    // stage B tile 0 into P[1]
    {
        uint4 r0[4];
        const int G0 = tid * 4;
        #pragma unroll
        for (int k = 0; k < 4; ++k) {
            int G = G0 + k, row = G >> 4, g = G & 15;
            r0[k] = *(const uint4*)&xp[(size_t)(colT0 * 64 + row) * 128 + g * 8];
        }
        float xv = (tid < 64) ? xxf[(b << 12) + colT0 * 64 + tid] : 0.f;
        #pragma unroll
        for (int k = 0; k < 4; ++k) {
            int G = G0 + k, row = G >> 4, g = G & 15;
            *(uint4*)&P[1][row * 136 + g * 8] = r0[k];
        }
        if (tid < 64) xxm[0][tid] = xv;
    }
    __syncthreads();

    // per-lane: 4 row-lists (rows wave*16+quad*4+r), each sorted-desc 8 keys
    unsigned int keys[4][8];
    #pragma unroll
    for (int r = 0; r < 4; ++r)
        #pragma unroll
        for (int j = 0; j < 8; ++j) keys[r][j] = 0u;

    for (int mt = 0; mt < 32; ++mt) {
        unsigned short* cur = P[1 - (mt & 1)];
        unsigned short* nxt = P[mt & 1];

        uint4 pr[4]; float pxv = 0.f;
        const int G0 = tid * 4;
        if (mt + 1 < 32) {
            const int tnext = colT0 + mt + 1;
            #pragma unroll
            for (int k = 0; k < 4; ++k) {
                int G = G0 + k, row = G >> 4, g = G & 15;
                pr[k] = *(const uint4*)&xp[(size_t)(tnext * 64 + row) * 128 + g * 8];
            }
            if (tid < 64) pxv = xxf[(b << 12) + tnext * 64 + tid];
        }

        #pragma unroll
        for (int ct = 0; ct < 4; ++ct) {
            const int brow = (ct * 16 + lrow) * 136;
            short8 bh0 = *(const short8*)&cur[brow + quad * 8];
            short8 bh1 = *(const short8*)&cur[brow + 32 + quad * 8];
            short8 bl0 = *(const short8*)&cur[brow + 64 + quad * 8];
            short8 bl1 = *(const short8*)&cur[brow + 96 + quad * 8];
            f32x4 acc = {0.f, 0.f, 0.f, 0.f};
            acc = __builtin_amdgcn_mfma_f32_16x16x32_bf16(al0, bl0, acc, 0, 0, 0);
            acc = __builtin_amdgcn_mfma_f32_16x16x32_bf16(al1, bl1, acc, 0, 0, 0);
            acc = __builtin_amdgcn_mfma_f32_16x16x32_bf16(ah0, bl0, acc, 0, 0, 0);
            acc = __builtin_amdgcn_mfma_f32_16x16x32_bf16(ah1, bl1, acc, 0, 0, 0);
            acc = __builtin_amdgcn_mfma_f32_16x16x32_bf16(al0, bh0, acc, 0, 0, 0);
            acc = __builtin_amdgcn_mfma_f32_16x16x32_bf16(al1, bh1, acc, 0, 0, 0);
            acc = __builtin_amdgcn_mfma_f32_16x16x32_bf16(ah0, bh0, acc, 0, 0, 0);
            acc = __builtin_amdgcn_mfma_f32_16x16x32_bf16(ah1, bh1, acc, 0, 0, 0);
            const float xm = xxm[mt & 1][ct * 16 + lrow];
            const unsigned int p = (unsigned int)(mt * 4 + ct);
            #pragma unroll
            for (int r = 0; r < 4; ++r) {
                float v = 2.f * acc[r] - xm;
                unsigned int u = __float_as_uint(v);
                unsigned int key = u ^ ((unsigned int)(((int)u) >> 31) | 0x80000000u);
                key = (key & 0xFFFFFF80u) | p;
                // branchless sorted insert (desc)
                unsigned int t = key;
                #pragma unroll
                for (int j = 0; j < 8; ++j) {
                    unsigned int mx = keys[r][j] > t ? keys[r][j] : t;
                    unsigned int mn = keys[r][j] > t ? t : keys[r][j];
                    keys[r][j] = mx; t = mn;
                }
            }
        }

        if (mt + 1 < 32) {
            #pragma unroll
            for (int k = 0; k < 4; ++k) {
                int G = G0 + k, row = G >> 4, g = G & 15;
                *(uint4*)&nxt[row * 136 + g * 8] = pr[k];
            }
            if (tid < 64) xxm[(mt + 1) & 1][tid] = pxv;
        }
        __syncthreads();
    }

    // dump keys: mK[row][lrow*8 + j], row = wave*16 + quad*4 + r   (32 KB <= 34816 B)
    unsigned int* mK = (unsigned int*)&P[0][0];
    const int mrow = wave * 16 + quad * 4;
    #pragma unroll
    for (int r = 0; r < 4; ++r) {
        uint4 k0 = make_uint4(keys[r][0], keys[r][1], keys[r][2], keys[r][3]);
        uint4 k1 = make_uint4(keys[r][4], keys[r][5], keys[r][6], keys[r][7]);
        *(uint4*)&mK[(mrow + r) * 128 + lrow * 8]     = k0;
        *(uint4*)&mK[(mrow + r) * 128 + lrow * 8 + 4] = k1;
    }
    __syncthreads();

    if (tid < 64) {
        unsigned int bk[NCH]; int bc[NCH];
        #pragma unroll
        for (int j = 0; j < NCH; ++j) { bk[j] = 0u; bc[j] = 0; }
        const unsigned int* rowK = mK + tid * 128;
        for (int c = 0; c < 128; ++c) {
            int pos = (tid + c) & 127;
            unsigned int k = rowK[pos];
            if (k > bk[NCH - 1]) {
                int lr = pos >> 3;
                int p  = (int)(k & 0x7Fu);
                int col = ((colT0 + (p >> 2)) << 6) + ((p & 3) << 4) + lr;
                bk[NCH - 1] = k; bc[NCH - 1] = col;
                #pragma unroll
                for (int j = NCH - 1; j > 0; --j) {
                    if (bk[j] > bk[j - 1]) {
                        unsigned int tk = bk[j]; bk[j] = bk[j - 1]; bk[j - 1] = tk;
                        int tc = bc[j]; bc[j] = bc[j - 1]; bc[j - 1] = tc;
                    }
                }
            }
        }
        int* co = cand + ((size_t)((b << 12) + n0 + tid)) * NCT + half * NCH;
        #pragma unroll
        for (int j = 0; j < NCH; ++j) co[j] = bc[j];
    }
}

// ---------------- Kernel 3: exact fp64 re-rank of 32 candidates + gather/max -> feat ----------------
__global__ __launch_bounds__(256) void rerank_kernel(const float* __restrict__ x,
                                                     const double* __restrict__ xxd,
                                                     const int* __restrict__ cand,
                                                     float* __restrict__ feat) {
    __shared__ double sc[4][NCT];
    __shared__ int    si[4][NCT];
    __shared__ int    sel[4][KNN];
    const int tid = threadIdx.x, wave = tid >> 6, lane = tid & 63;
    const size_t row = (size_t)blockIdx.x * 4 + wave;     // 0..32767
    const int b = (int)(row >> 12);
    const float* xb = x + (((size_t)b) << 12) * CIN;
    const float* xn = x + row * CIN;

    const int cidx = lane & 31, part = lane >> 5;
    int m = cand[row * NCT + cidx];
    {
        const float* xm = xb + (size_t)m * CIN;
        const float* xa = xn + part * 32;
        const float* xv = xm + part * 32;
        double d = 0.0;
        #pragma unroll
        for (int c4 = 0; c4 < 8; ++c4) {
            float4 a = *(const float4*)&xa[c4 * 4];
            float4 v = *(const float4*)&xv[c4 * 4];
            d = fma((double)a.x, (double)v.x, d);
            d = fma((double)a.y, (double)v.y, d);
            d = fma((double)a.z, (double)v.z, d);
            d = fma((double)a.w, (double)v.w, d);
        }
        d += __shfl_xor(d, 32);
        if (part == 0) {
            sc[wave][cidx] = 2.0 * d - xxd[(((size_t)b) << 12) + m];
            si[wave][cidx] = m;
        }
    }
    __syncthreads();

    if (lane == 0) {
        double fd[KNN]; int fi[KNN];
        #pragma unroll
        for (int j = 0; j < KNN; ++j) { fd[j] = -1.0e300; fi[j] = 0; }
        for (int c = 0; c < NCT; ++c) {
            double v = sc[wave][c];
            if (v > fd[KNN - 1]) {
                fd[KNN - 1] = v; fi[KNN - 1] = si[wave][c];
                #pragma unroll
                for (int j = KNN - 1; j > 0; --j) {
                    if (fd[j] > fd[j - 1]) {
                        double td = fd[j]; fd[j] = fd[j - 1]; fd[j - 1] = td;
                        int    ti = fi[j]; fi[j] = fi[j - 1]; fi[j - 1] = ti;
                    }
                }
            }
        }
        #pragma unroll
        for (int j = 0; j < KNN; ++j) sel[wave][j] = fi[j];
    }
    __syncthreads();

    float mx = -3.0e38f;
    #pragma unroll
    for (int j = 0; j < KNN; ++j)
        mx = fmaxf(mx, xb[(size_t)sel[wave][j] * CIN + lane]);
    feat[row * CIN + lane] = mx;
}

// ---------------- Kernel 4: conv (fp32 VALU) -> y + BN stats ----------------
__global__ __launch_bounds__(256) void conv_stats_kernel(const float* __restrict__ feat,
                                                         const float* __restrict__ W,
                                                         float* __restrict__ y,
                                                         float* __restrict__ st) {
    __shared__ float Wt[64 * 128];   // Wt[c][o]
    __shared__ float Fs[64 * 64];
    __shared__ float bs[128], bs2[128];
    const int tid = threadIdx.x;
    const int n0  = blockIdx.x * 64;

    for (int i = tid; i < 8192; i += 256) {
        int o = i >> 6, c = i & 63;
        Wt[c * 128 + o] = W[i];
    }
    for (int i = tid; i < 1024; i += 256)
        ((float4*)Fs)[i] = ((const float4*)(feat + (size_t)n0 * CIN))[i];
    if (tid < 128) { bs[tid] = 0.f; bs2[tid] = 0.f; }
    __syncthreads();

    const int og = tid & 31, rg = tid >> 5;
    float ts[4] = {0.f, 0.f, 0.f, 0.f}, ts2[4] = {0.f, 0.f, 0.f, 0.f};
    #pragma unroll
    for (int p = 0; p < 4; ++p) {
        const int r0 = p * 16 + rg * 2;
        float acc0[4] = {0.f, 0.f, 0.f, 0.f}, acc1[4] = {0.f, 0.f, 0.f, 0.f};
        for (int c = 0; c < 64; ++c) {
            float f0 = Fs[r0 * 64 + c], f1 = Fs[(r0 + 1) * 64 + c];
            #pragma unroll
            for (int j = 0; j < 4; ++j) {
                float w = Wt[c * 128 + og + 32 * j];
                acc0[j] += f0 * w; acc1[j] += f1 * w;
            }
        }
        #pragma unroll
        for (int j = 0; j < 4; ++j) {
            const int ch = og + 32 * j;
            y[(size_t)(n0 + r0)     * COUT + ch] = acc0[j];
            y[(size_t)(n0 + r0 + 1) * COUT + ch] = acc1[j];
            ts[j]  += acc0[j] + acc1[j];
            ts2[j] += acc0[j] * acc0[j] + acc1[j] * acc1[j];
        }
    }
    #pragma unroll
    for (int j = 0; j < 4; ++j) {
        atomicAdd(&bs [og + 32 * j], ts[j]);
        atomicAdd(&bs2[og + 32 * j], ts2[j]);
    }
    __syncthreads();
    if (tid < 128) {
        atomicAdd(&st[tid],       bs[tid]);
        atomicAdd(&st[128 + tid], bs2[tid]);
    }
}

// ---------------- Kernel 5: elementwise BN + LeakyReLU -> fp32 out ----------------
__global__ __launch_bounds__(256) void norm_out_kernel(const float* __restrict__ y,
                                                       const float* __restrict__ st,
                                                       const float* __restrict__ gamma,
                                                       const float* __restrict__ beta,
                                                       float* __restrict__ out) {
    size_t i = ((size_t)blockIdx.x * 256 + threadIdx.x) * 4;
    int c0 = (int)(i & 127);
    float4 v = *(const float4*)&y[i];
    float o[4];
    const float inv = 1.0f / (float)TOTROWS;
    #pragma unroll
    for (int j = 0; j < 4; ++j) {
        int c = c0 + j;
        float m  = st[c] * inv;
        float vr = st[128 + c] * inv - m * m;
        float sc = rsqrtf(vr + 1e-5f) * gamma[c];
        float t  = (((const float*)&v)[j] - m) * sc + beta[c];
        o[j] = (t >= 0.f) ? t : 0.01f * t;
    }
    *(float4*)&out[i] = make_float4(o[0], o[1], o[2], o[3]);
}

extern "C" void kernel_launch(void* const* d_in, const int* in_sizes, int n_in,
                              void* d_out, int out_size, void* d_ws, size_t ws_size,
                              hipStream_t stream) {
    (void)in_sizes; (void)n_in; (void)out_size; (void)ws_size;
    const float* x     = (const float*)d_in[0];
    const float* W     = (const float*)d_in[1];
    const float* gamma = (const float*)d_in[2];
    const float* beta  = (const float*)d_in[3];
    // d_in[4] is k == 8 (compile-time KNN)
    float* out = (float*)d_out;

    // workspace (~28.4 MB): xxf 128K | xxd 256K | cand 4M | feat 8M | xpack 16M (reused as y) | st 1K
    char*   ws    = (char*)d_ws;
    float*  xxf   = (float*)ws;
    double* xxd   = (double*)(ws + 131072);
    int*    cand  = (int*)(ws + 131072 + 262144);
    float*  feat  = (float*)(ws + 131072 + 262144 + 4194304);
    unsigned short* xpack = (unsigned short*)(ws + 131072 + 262144 + 4194304 + 8388608);
    float*  y     = (float*)xpack;   // xpack dead after knn_cand; y is 16 MB fp32
    float*  st    = (float*)(ws + 131072 + 262144 + 4194304 + 8388608 + 16777216);

    hipMemsetAsync(st, 0, 256 * sizeof(float), stream);
    prep_kernel      <<<TOTROWS * 8 / 256, 256, 0, stream>>>(x, xpack, xxf, xxd);
    knn_cand_kernel  <<<dim3(NPTS / 64, 2, BATCH), 256, 0, stream>>>(xpack, xxf, cand);
    rerank_kernel    <<<TOTROWS / 4, 256, 0, stream>>>(x, xxd, cand, feat);
    conv_stats_kernel<<<TOTROWS / 64, 256, 0, stream>>>(feat, W, y, st);
    norm_out_kernel  <<<(TOTROWS * COUT) / (256 * 4), 256, 0, stream>>>(y, st, gamma, beta, out);
}